// Round 1
// baseline (409.824 us; speedup 1.0000x reference)
//
#include <hip/hip_runtime.h>

// Segment-sum over sorted ray indices + gather-back.
//   d_in[0]: sample_values f32 [n_samples * D]
//   d_in[1]: ray_indices  i32 [n_samples] (sorted)
//   d_in[2]: n_rays (device scalar, unused -- derived from sizes)
//   d_out  : [n_rays*D] per-ray sums, then [n_samples*D] per-sample gathered sums

#define DCH 8        // feature dim (verified against in_sizes at launch)
#define KPT 16       // consecutive samples per thread in pass 1

__global__ void __launch_bounds__(256) segsum_kernel(
    const float* __restrict__ vals,
    const int* __restrict__ rays,
    float* __restrict__ out_ray,
    int n_samples) {
  long tid = (long)blockIdx.x * blockDim.x + threadIdx.x;
  long base = tid * KPT;
  if (base >= n_samples) return;
  long end = base + KPT;
  if (end > n_samples) end = n_samples;

  int cur = rays[base];
  float acc[DCH];
#pragma unroll
  for (int c = 0; c < DCH; ++c) acc[c] = 0.f;

  for (long j = base; j < end; ++j) {
    int r = rays[j];
    if (r != cur) {
      float* dst = out_ray + (long)cur * DCH;
#pragma unroll
      for (int c = 0; c < DCH; ++c) atomicAdd(&dst[c], acc[c]);
#pragma unroll
      for (int c = 0; c < DCH; ++c) acc[c] = 0.f;
      cur = r;
    }
    const float4* v = reinterpret_cast<const float4*>(vals + j * DCH);
    float4 a = v[0];
    float4 b = v[1];
    acc[0] += a.x; acc[1] += a.y; acc[2] += a.z; acc[3] += a.w;
    acc[4] += b.x; acc[5] += b.y; acc[6] += b.z; acc[7] += b.w;
  }
  float* dst = out_ray + (long)cur * DCH;
#pragma unroll
  for (int c = 0; c < DCH; ++c) atomicAdd(&dst[c], acc[c]);
}

__global__ void __launch_bounds__(256) gather_kernel(
    const int* __restrict__ rays,
    const float* __restrict__ per_ray,
    float* __restrict__ out_sample,
    int n_samples) {
  long i = (long)blockIdx.x * blockDim.x + threadIdx.x;
  if (i >= n_samples) return;
  int r = rays[i];
  const float4* src = reinterpret_cast<const float4*>(per_ray + (long)r * DCH);
  float4 a = src[0];
  float4 b = src[1];
  float4* dst = reinterpret_cast<float4*>(out_sample + i * DCH);
  dst[0] = a;
  dst[1] = b;
}

extern "C" void kernel_launch(void* const* d_in, const int* in_sizes, int n_in,
                              void* d_out, int out_size, void* d_ws, size_t ws_size,
                              hipStream_t stream) {
  const float* vals = (const float*)d_in[0];
  const int* rays   = (const int*)d_in[1];

  const int n_samples = in_sizes[1];
  const int d         = in_sizes[0] / n_samples;   // = 8
  const int n_rays    = out_size / d - n_samples;  // = 65536

  float* out_ray    = (float*)d_out;
  float* out_sample = out_ray + (size_t)n_rays * d;

  // Zero the per-ray accumulator region (harness poisons d_out each launch).
  hipMemsetAsync(out_ray, 0, (size_t)n_rays * d * sizeof(float), stream);

  const int threads1 = (n_samples + KPT - 1) / KPT;
  segsum_kernel<<<(threads1 + 255) / 256, 256, 0, stream>>>(
      vals, rays, out_ray, n_samples);

  gather_kernel<<<((long)n_samples + 255) / 256, 256, 0, stream>>>(
      rays, out_ray, out_sample, n_samples);
}

// Round 4
// 258.034 us; speedup vs baseline: 1.5883x; 1.5883x over previous
//
#include <hip/hip_runtime.h>

// Segment-sum over sorted ray indices + gather-back.
//   d_in[0]: sample_values f32 [n_samples * D]
//   d_in[1]: ray_indices  i32 [n_samples] (sorted, non-decreasing)
//   d_in[2]: n_rays (device scalar, unused -- derived from sizes)
//   d_out  : [n_rays*D] per-ray sums, then [n_samples*D] per-sample gathered sums
//
// Pass 1: wave-cooperative segmented scan. 2 lanes per sample (half h = lane&1
// owns 4 of the 8 channels). Loads are perfectly coalesced (wave reads 1 KB
// contiguous). Segments (equal ray id, contiguous because sorted) are summed
// with a 5-step predicated shuffle-up scan; only segment-closing lanes issue
// atomics (~0.6M f32 atomics total vs 21M in the naive run-per-thread version).

#define DCH 8

__device__ __forceinline__ float4 shfl_up4(float4 v, int d) {
  float4 r;
  r.x = __shfl_up(v.x, d, 64);
  r.y = __shfl_up(v.y, d, 64);
  r.z = __shfl_up(v.z, d, 64);
  r.w = __shfl_up(v.w, d, 64);
  return r;
}

__device__ __forceinline__ float4 shfl4(float4 v, int src) {
  float4 r;
  r.x = __shfl(v.x, src, 64);
  r.y = __shfl(v.y, src, 64);
  r.z = __shfl(v.z, src, 64);
  r.w = __shfl(v.w, src, 64);
  return r;
}

__device__ __forceinline__ void atomic_add4(float* dst, float4 v) {
  atomicAdd(dst + 0, v.x);
  atomicAdd(dst + 1, v.y);
  atomicAdd(dst + 2, v.z);
  atomicAdd(dst + 3, v.w);
}

__global__ void __launch_bounds__(256) segsum_kernel(
    const float* __restrict__ vals,
    const int* __restrict__ rays,
    float* __restrict__ out_ray,
    int n_samples, int spw /* samples per wave, multiple of 32 */) {
  const int lane = threadIdx.x & 63;
  const int sl = lane >> 1;  // sample slot within window [0,32)
  const int h = lane & 1;    // channel half (h*4 .. h*4+3)
  const long wid = (long)blockIdx.x * (blockDim.x >> 6) + (threadIdx.x >> 6);

  long chunk = wid * (long)spw;
  if (chunk >= n_samples) return;
  long chunk_end = chunk + spw;
  if (chunk_end > n_samples) chunk_end = n_samples;

  int carry_r = -1;
  float4 carry_v = {0.f, 0.f, 0.f, 0.f};

  for (long wb = chunk; wb < chunk_end; wb += 32) {
    long s = wb + sl;
    int r = -1;
    float4 v = {0.f, 0.f, 0.f, 0.f};
    if (s < chunk_end) {
      r = rays[s];
      v = *reinterpret_cast<const float4*>(vals + s * DCH + (long)h * 4);
    }

    // Resolve carry from previous window: continue into first segment, or flush.
    int r0 = __shfl(r, 0, 64);
    bool cont = (r0 == carry_r);
    if (!cont && carry_r >= 0 && sl == 0) {
      atomic_add4(out_ray + (long)carry_r * DCH + h * 4, carry_v);
    }
    if (cont && sl == 0) {
      v.x += carry_v.x; v.y += carry_v.y; v.z += carry_v.z; v.w += carry_v.w;
    }

    // Segmented inclusive scan over the 32 sample slots (pair-aligned offsets).
#pragma unroll
    for (int off = 2; off <= 32; off <<= 1) {
      float4 vo = shfl_up4(v, off);
      int ro = __shfl_up(r, off, 64);
      if (lane >= off && ro == r) {
        v.x += vo.x; v.y += vo.y; v.z += vo.z; v.w += vo.w;
      }
    }

    int rn = __shfl_down(r, 2, 64);
    bool last_in_win = (sl == 31);
    bool seg_last = last_in_win || (rn != r);

    // Flush segments that close strictly inside the window.
    if (seg_last && !last_in_win && r >= 0) {
      atomic_add4(out_ray + (long)r * DCH + h * 4, v);
    }

    // Trailing (open) segment becomes the new carry.
    carry_r = __shfl(r, 62 + h, 64);
    carry_v = shfl4(v, 62 + h);
  }

  if (carry_r >= 0 && sl == 0) {
    atomic_add4(out_ray + (long)carry_r * DCH + h * 4, carry_v);
  }
}

// Pass 2: one thread per float4 (2 threads per sample). Contiguous 16B stores.
__global__ void __launch_bounds__(256) gather_kernel(
    const int* __restrict__ rays,
    const float* __restrict__ per_ray,
    float4* __restrict__ out4,
    long n_half /* n_samples * 2 */) {
  long t = (long)blockIdx.x * blockDim.x + threadIdx.x;
  if (t >= n_half) return;
  long s = t >> 1;
  int h = (int)t & 1;
  int r = rays[s];
  out4[t] = *reinterpret_cast<const float4*>(per_ray + (long)r * DCH + h * 4);
}

extern "C" void kernel_launch(void* const* d_in, const int* in_sizes, int n_in,
                              void* d_out, int out_size, void* d_ws, size_t ws_size,
                              hipStream_t stream) {
  const float* vals = (const float*)d_in[0];
  const int* rays   = (const int*)d_in[1];

  const int n_samples = in_sizes[1];
  const int d         = in_sizes[0] / n_samples;   // = 8
  const int n_rays    = out_size / d - n_samples;  // = 65536

  float* out_ray    = (float*)d_out;
  float* out_sample = out_ray + (size_t)n_rays * d;

  // Zero the per-ray accumulator region (harness poisons d_out each launch).
  (void)hipMemsetAsync(out_ray, 0, (size_t)n_rays * d * sizeof(float), stream);

  // Pass 1: ~8192 waves; each wave owns a contiguous chunk of samples.
  const int nblocks1 = 2048;
  const int waves_per_block = 256 / 64;
  const long total_waves = (long)nblocks1 * waves_per_block;
  int spw = (int)((n_samples + total_waves - 1) / total_waves);
  spw = (spw + 31) & ~31;  // multiple of 32
  segsum_kernel<<<nblocks1, 256, 0, stream>>>(vals, rays, out_ray, n_samples, spw);

  // Pass 2.
  const long n_half = (long)n_samples * 2;
  const long nblocks2 = (n_half + 255) / 256;
  gather_kernel<<<(int)nblocks2, 256, 0, stream>>>(
      rays, out_ray, reinterpret_cast<float4*>(out_sample), n_half);
}